// Round 2
// baseline (344.297 us; speedup 1.0000x reference)
//
#include <hip/hip_runtime.h>
#include <math.h>

#define NH 16
#define NB 64
#define DK 64
#define NE 32768

typedef float vf4 __attribute__((ext_vector_type(4)));  // clang vector: OK for nontemporal builtins

// ws layout: [0..127] int bounds[NB+1] (padded to 512B), then float ksc[NH*NE].
// M,inv per (h,b) are stashed in out[h,b,0], out[h,b,1] — consumed by kernel B,
// then overwritten by kernel C's final store. Stream order A->B->C makes this safe.

// Kernel 0: segment bounds from sorted batch. bounds[b] = min{e : batch[e] >= b}.
__global__ void seg_bounds_kernel(const int* __restrict__ batch, int* __restrict__ bounds) {
    int e = blockIdx.x * 256 + threadIdx.x;
    if (e >= NE) return;
    int be = batch[e];
    if (e == 0) {
        for (int b = 0; b <= be; ++b) bounds[b] = 0;
    } else {
        int bp = batch[e - 1];
        for (int b = bp + 1; b <= be; ++b) bounds[b] = e;
    }
    if (e == NE - 1) {
        for (int b = be + 1; b <= NB; ++b) bounds[b] = NE;
    }
}

// Kernel A: one block per (h,b). Scores into ksc, (M, 1/L) into out-stash.
// Pure K-read stream + tiny writes; no work after the reduction.
__global__ __launch_bounds__(512) void scores_kernel(
    const float* __restrict__ Q,      // [NH, NB, DK]
    const float* __restrict__ K,      // [NH, NE, DK]
    const int*   __restrict__ bounds, // [NB+1]
    float* __restrict__ ksc_base,     // [NH, NE]
    float* __restrict__ stash)        // = out [NH, NB, DK]; writes [h,b,0..1]
{
    const int b    = blockIdx.x;
    const int h    = blockIdx.y;
    const int tid  = threadIdx.x;
    const int wave = tid >> 6;
    const int lane = tid & 63;

    const int start = bounds[b];
    const int end   = bounds[b + 1];

    float* ksc = ksc_base + (size_t)h * NE;

    __shared__ float qs[DK];
    __shared__ float sm[8], sl[8];

    if (tid < DK) qs[tid] = Q[((size_t)h * NB + b) * DK + tid];
    __syncthreads();

    // thread-per-edge scores; 16 independent float4 loads per edge = deep MLP
    const float4* q4 = (const float4*)qs;
    float m = -INFINITY, l = 0.f;
    for (int e = start + tid; e < end; e += 512) {
        const float4* kr = (const float4*)(K + ((size_t)h * NE + e) * DK);
        float sx = 0.f, sy = 0.f, sz = 0.f, sw = 0.f;
        #pragma unroll
        for (int i = 0; i < DK / 4; ++i) {
            float4 kv = kr[i];
            float4 qv = q4[i];
            sx = fmaf(kv.x, qv.x, sx);
            sy = fmaf(kv.y, qv.y, sy);
            sz = fmaf(kv.z, qv.z, sz);
            sw = fmaf(kv.w, qv.w, sw);
        }
        float s = (sx + sy) + (sz + sw);
        ksc[e] = s;
        float nm = fmaxf(m, s);
        l = l * __expf(m - nm) + __expf(s - nm);
        m = nm;
    }

    // wave-level (m,l) butterfly merge
    #pragma unroll
    for (int off = 32; off; off >>= 1) {
        float om = __shfl_xor(m, off);
        float ol = __shfl_xor(l, off);
        float nm = fmaxf(m, om);
        float t1 = (l  > 0.f) ? l  * __expf(m  - nm) : 0.f;
        float t2 = (ol > 0.f) ? ol * __expf(om - nm) : 0.f;
        m = nm; l = t1 + t2;
    }
    if (lane == 0) { sm[wave] = m; sl[wave] = l; }
    __syncthreads();

    if (tid == 0) {
        float M = -INFINITY;
        #pragma unroll
        for (int w = 0; w < 8; ++w) M = fmaxf(M, sm[w]);
        float L = 0.f;
        #pragma unroll
        for (int w = 0; w < 8; ++w) L += (sl[w] > 0.f) ? sl[w] * __expf(sm[w] - M) : 0.f;
        const float inv = (L > 0.f) ? 1.f / L : 0.f;
        stash[((size_t)h * NB + b) * DK + 0] = M;
        stash[((size_t)h * NB + b) * DK + 1] = inv;
    }
}

// Kernel B: write the ENTIRE attn array [NH,NB,NE] as one coalesced nontemporal
// write stream. One vf4 (4 edges) per thread. Only ~2% of waves touch a segment
// (1/64 density), so the exp path is exec-mask-skipped almost everywhere.
// Each 256-thread block covers one (h,b) slice (NE/4 = 8192 divisible by 256),
// so M/inv loads are block-uniform.
__global__ __launch_bounds__(256) void attn_write_kernel(
    const int*   __restrict__ batch,    // [NE]
    const float* __restrict__ ksc_base, // [NH, NE]
    const float* __restrict__ stash,    // = out; reads [h,b,0..1]
    float* __restrict__ attn)           // [NH, NB, NE]
{
    const unsigned idx = blockIdx.x * 256u + threadIdx.x;   // vf4 index, < NH*NB*NE/4
    const int e4 = idx & (NE / 4 - 1);
    const int bh = idx >> 13;            // NE/4 = 8192 = 2^13; bh = h*NB + b
    const int b  = bh & (NB - 1);
    const int e0 = e4 << 2;

    const int4 bt = *(const int4*)(batch + e0);
    vf4 r = (vf4)(0.f);
    if (bt.x == b || bt.y == b || bt.z == b || bt.w == b) {
        const float M   = stash[(size_t)bh * DK + 0];
        const float inv = stash[(size_t)bh * DK + 1];
        const int h = bh >> 6;           // bh / NB
        const float4 s = *(const float4*)(ksc_base + (size_t)h * NE + e0);
        if (bt.x == b) r.x = __expf(s.x - M) * inv;
        if (bt.y == b) r.y = __expf(s.y - M) * inv;
        if (bt.z == b) r.z = __expf(s.z - M) * inv;
        if (bt.w == b) r.w = __expf(s.w - M) * inv;
    }
    __builtin_nontemporal_store(r, (vf4*)attn + idx);
}

// Kernel C: out[h,b,d] = sum_e attn[h,b,e] * V[h,e,d]. Reads normalized p
// straight from attn (no exp in the hot loop). Pure V-read stream.
// lane = d; contiguous chunk of the segment per wave; unroll 4.
__global__ __launch_bounds__(512) void out_kernel(
    const float* __restrict__ V,      // [NH, NE, DK]
    const int*   __restrict__ bounds, // [NB+1]
    const float* __restrict__ attn,   // [NH, NB, NE]
    float* __restrict__ out)          // [NH, NB, DK]
{
    const int b    = blockIdx.x;
    const int h    = blockIdx.y;
    const int tid  = threadIdx.x;
    const int wave = tid >> 6;
    const int lane = tid & 63;

    const int start = bounds[b];
    const int end   = bounds[b + 1];

    const float* arow = attn + ((size_t)h * NB + b) * NE;

    __shared__ float red[8][DK];

    const int S   = end - start;
    const int per = (S + 7) >> 3;
    const int cb  = start + wave * per;
    const int ce  = (cb + per < end) ? cb + per : end;

    float a0 = 0.f, a1 = 0.f, a2 = 0.f, a3 = 0.f;
    int e = cb;
    for (; e + 3 < ce; e += 4) {
        float p0 = arow[e];
        float p1 = arow[e + 1];
        float p2 = arow[e + 2];
        float p3 = arow[e + 3];
        const float* vb = V + ((size_t)h * NE + e) * DK + lane;
        a0 = fmaf(p0, vb[0 * DK], a0);
        a1 = fmaf(p1, vb[1 * DK], a1);
        a2 = fmaf(p2, vb[2 * DK], a2);
        a3 = fmaf(p3, vb[3 * DK], a3);
    }
    for (; e < ce; ++e) {
        float p = arow[e];
        a0 = fmaf(p, V[((size_t)h * NE + e) * DK + lane], a0);
    }
    red[wave][lane] = (a0 + a1) + (a2 + a3);
    __syncthreads();
    if (wave == 0) {
        float r = 0.f;
        #pragma unroll
        for (int w = 0; w < 8; ++w) r += red[w][lane];
        out[((size_t)h * NB + b) * DK + lane] = r;   // overwrites the M/inv stash — safe, B already consumed it
    }
}

extern "C" void kernel_launch(void* const* d_in, const int* in_sizes, int n_in,
                              void* d_out, int out_size, void* d_ws, size_t ws_size,
                              hipStream_t stream) {
    const float* Q     = (const float*)d_in[0];
    const float* K     = (const float*)d_in[1];
    const float* V     = (const float*)d_in[2];
    const int*   batch = (const int*)d_in[3];

    float* out  = (float*)d_out;                    // [NH,NB,DK]
    float* attn = out + (size_t)NH * NB * DK;       // [NH,NB,NE]

    int*   bounds = (int*)d_ws;                     // [NB+1], padded to 512 B
    float* ksc    = (float*)d_ws + 128;             // [NH,NE]

    seg_bounds_kernel<<<NE / 256, 256, 0, stream>>>(batch, bounds);

    dim3 grid(NB, NH);
    scores_kernel<<<grid, 512, 0, stream>>>(Q, K, bounds, ksc, out);

    const unsigned nvf4 = (unsigned)NH * NB * (NE / 4);          // 8,388,608
    attn_write_kernel<<<nvf4 / 256, 256, 0, stream>>>(batch, ksc, out, attn);

    out_kernel<<<grid, 512, 0, stream>>>(V, bounds, attn, out);
}

// Round 3
// 343.446 us; speedup vs baseline: 1.0025x; 1.0025x over previous
//
#include <hip/hip_runtime.h>
#include <math.h>

#define NH 16
#define NB 64
#define DK 64
#define NE 32768

typedef float vf4 __attribute__((ext_vector_type(4)));  // clang vector: OK for nontemporal builtins

// ws layout (floats): [0..127] int bounds[NB+1] (padded to 512B)
//                     [128 .. 128+NH*NE)          float ksc[NH*NE]
//                     [128+NH*NE .. +4096)        float mstash[NH*NB][2][2]  (M,L per half-segment)

// Kernel 0: segment bounds from sorted batch. bounds[b] = min{e : batch[e] >= b}.
__global__ void seg_bounds_kernel(const int* __restrict__ batch, int* __restrict__ bounds) {
    int e = blockIdx.x * 256 + threadIdx.x;
    if (e >= NE) return;
    int be = batch[e];
    if (e == 0) {
        for (int b = 0; b <= be; ++b) bounds[b] = 0;
    } else {
        int bp = batch[e - 1];
        for (int b = bp + 1; b <= be; ++b) bounds[b] = e;
    }
    if (e == NE - 1) {
        for (int b = be + 1; b <= NB; ++b) bounds[b] = NE;
    }
}

// Kernel A: 2048 blocks x 256. Block g handles half-segment (task = g>>1, half = g&1).
// GROUP-COALESCED K reads: wave processes 4 edges/iter; lane j=lane>>4 picks the edge,
// c=lane&15 picks the float4 d-chunk -> each load instruction is 1KB CONTIGUOUS
// (8 cache-line requests) instead of 64 scattered 16B requests (the old 256B-stride
// pattern). Intra-group shfl reduce gives the dot; per-lane online (m,l).
__global__ __launch_bounds__(256) void scores_kernel(
    const float* __restrict__ Q,      // [NH, NB, DK]
    const float* __restrict__ K,      // [NH, NE, DK]
    const int*   __restrict__ bounds, // [NB+1]
    float* __restrict__ ksc_base,     // [NH, NE]
    float* __restrict__ mstash)       // [NH*NB][2][2]
{
    const int g    = blockIdx.x;       // 0..2047
    const int task = g >> 1;           // h*NB + b
    const int half = g & 1;
    const int h    = task >> 6;
    const int b    = task & (NB - 1);
    const int tid  = threadIdx.x;
    const int wave = tid >> 6;
    const int lane = tid & 63;
    const int j    = lane >> 4;        // edge offset within group of 4
    const int c    = lane & 15;        // float4 chunk of d

    const int start = bounds[b];
    const int end   = bounds[b + 1];
    const int S     = end - start;
    const int Sh    = (S + 1) >> 1;
    const int s0    = start + half * Sh;
    const int e1    = (s0 + Sh < end) ? s0 + Sh : end;

    float* ksc = ksc_base + (size_t)h * NE;

    __shared__ float qs[DK];
    __shared__ float sm[4], sl[4];
    if (tid < DK) qs[tid] = Q[((size_t)h * NB + b) * DK + tid];
    __syncthreads();

    const float4 qc = ((const float4*)qs)[c];
    const float4* K4 = (const float4*)(K + (size_t)h * NE * DK);

    float m = -INFINITY, l = 0.f;
    for (int e = s0 + wave * 4; e < e1; e += 16) {
        const int  ej    = e + j;
        const bool valid = ej < e1;
        const int  el    = valid ? ej : e1 - 1;       // e1-1 >= s0 >= 0 when loop entered
        const float4 kv = K4[(size_t)el * (DK / 4) + c];   // 1KB contiguous per wave instr
        float s = fmaf(kv.x, qc.x, fmaf(kv.y, qc.y, fmaf(kv.z, qc.z, kv.w * qc.w)));
        // sum over the 16 c-lanes of this group -> full dot, broadcast to all 16
        #pragma unroll
        for (int off = 1; off < 16; off <<= 1)
            s += __shfl_xor(s, off);
        if (valid) {
            if (c == 0) ksc[ej] = s;                  // lanes 0,16,32,48: 4 consecutive floats
            float nm = fmaxf(m, s);
            l = l * __expf(m - nm) + __expf(s - nm);  // m=-inf first time: 0*exp(-inf)=0, safe
            m = nm;
        }
    }

    // merge the 4 j-groups (lanes with equal c hold identical (m,l))
    #pragma unroll
    for (int off = 16; off < 64; off <<= 1) {
        float om = __shfl_xor(m, off);
        float ol = __shfl_xor(l, off);
        float nm = fmaxf(m, om);
        float t1 = (l  > 0.f) ? l  * __expf(m  - nm) : 0.f;
        float t2 = (ol > 0.f) ? ol * __expf(om - nm) : 0.f;
        m = nm; l = t1 + t2;
    }
    if (lane == 0) { sm[wave] = m; sl[wave] = l; }
    __syncthreads();

    if (tid == 0) {
        float M = -INFINITY;
        #pragma unroll
        for (int w = 0; w < 4; ++w) M = fmaxf(M, sm[w]);
        float L = 0.f;
        #pragma unroll
        for (int w = 0; w < 4; ++w) L += (sl[w] > 0.f) ? sl[w] * __expf(sm[w] - M) : 0.f;
        mstash[(task * 2 + half) * 2 + 0] = M;
        mstash[(task * 2 + half) * 2 + 1] = L;
    }
}

// Kernel BC: 2048 blocks x 256. Blocks [0,1024): attn write stream (grid-stride vf4,
// nontemporal). Blocks [1024,2048): out = p·V with the same group-coalesced pattern
// as kernel A (1KB contiguous V loads). Write-blocks and read-blocks are co-resident
// per CU -> mixed read/write streams. Both consume the half-segment (M,L) stash.
__global__ __launch_bounds__(256) void bc_kernel(
    const int*   __restrict__ batch,    // [NE]
    const float* __restrict__ ksc_base, // [NH, NE]
    const float* __restrict__ mstash,   // [NH*NB][2][2]
    const float* __restrict__ V,        // [NH, NE, DK]
    const int*   __restrict__ bounds,   // [NB+1]
    float* __restrict__ attn,           // [NH, NB, NE]
    float* __restrict__ out)            // [NH, NB, DK]
{
    const int blk = blockIdx.x;
    const int tid = threadIdx.x;
    __shared__ float red[4][16][4];

    if (blk < 1024) {
        // ---- B: full attn array as one coalesced nontemporal write stream ----
        const unsigned total = (unsigned)NH * NB * (NE / 4);
        for (unsigned idx = blk * 256u + tid; idx < total; idx += 1024u * 256u) {
            const int e4 = idx & (NE / 4 - 1);
            const int bh = idx >> 13;            // NE/4 = 2^13
            const int b  = bh & (NB - 1);
            const int e0 = e4 << 2;
            const int4 bt = *(const int4*)(batch + e0);
            vf4 r = (vf4)(0.f);
            if (bt.x == b || bt.y == b || bt.z == b || bt.w == b) {
                const float m0 = mstash[bh * 4 + 0], l0 = mstash[bh * 4 + 1];
                const float m1 = mstash[bh * 4 + 2], l1 = mstash[bh * 4 + 3];
                const float M = fmaxf(m0, m1);
                float L = 0.f;
                if (l0 > 0.f) L += l0 * __expf(m0 - M);
                if (l1 > 0.f) L += l1 * __expf(m1 - M);
                const float inv = (L > 0.f) ? 1.f / L : 0.f;
                const int h = bh >> 6;
                const float4 s = *(const float4*)(ksc_base + (size_t)h * NE + e0);
                if (bt.x == b) r.x = __expf(s.x - M) * inv;
                if (bt.y == b) r.y = __expf(s.y - M) * inv;
                if (bt.z == b) r.z = __expf(s.z - M) * inv;
                if (bt.w == b) r.w = __expf(s.w - M) * inv;
            }
            __builtin_nontemporal_store(r, (vf4*)attn + idx);
        }
    } else {
        // ---- C: out[h,b,:] = sum_e p_e * V[e,:], group-coalesced V reads ----
        const int task = blk - 1024;             // h*NB + b
        const int h    = task >> 6;
        const int b    = task & (NB - 1);
        const int wave = tid >> 6;
        const int lane = tid & 63;
        const int j    = lane >> 4;
        const int c    = lane & 15;

        const int start = bounds[b];
        const int end   = bounds[b + 1];

        const float m0 = mstash[task * 4 + 0], l0 = mstash[task * 4 + 1];
        const float m1 = mstash[task * 4 + 2], l1 = mstash[task * 4 + 3];
        const float M = fmaxf(m0, m1);
        float L = 0.f;
        if (l0 > 0.f) L += l0 * __expf(m0 - M);
        if (l1 > 0.f) L += l1 * __expf(m1 - M);
        const float inv = (L > 0.f) ? 1.f / L : 0.f;

        const float*  ksc = ksc_base + (size_t)h * NE;
        const float4* V4  = (const float4*)(V + (size_t)h * NE * DK);

        float4 acc = make_float4(0.f, 0.f, 0.f, 0.f);
        for (int e = start + wave * 4; e < end; e += 16) {
            const int  ej    = e + j;
            const bool valid = ej < end;
            const int  el    = valid ? ej : end - 1;
            const float p = valid ? __expf(ksc[ej] - M) * inv : 0.f;  // same addr across c-lanes: 1 line
            const float4 v = V4[(size_t)el * (DK / 4) + c];           // 1KB contiguous per wave instr
            acc.x = fmaf(p, v.x, acc.x);
            acc.y = fmaf(p, v.y, acc.y);
            acc.z = fmaf(p, v.z, acc.z);
            acc.w = fmaf(p, v.w, acc.w);
        }
        // reduce over the 4 j-groups; c-lanes keep their d-chunk
        #pragma unroll
        for (int off = 16; off < 64; off <<= 1) {
            acc.x += __shfl_xor(acc.x, off);
            acc.y += __shfl_xor(acc.y, off);
            acc.z += __shfl_xor(acc.z, off);
            acc.w += __shfl_xor(acc.w, off);
        }
        if (lane < 16) {                         // j==0 lanes hold the wave sums
            red[wave][c][0] = acc.x;
            red[wave][c][1] = acc.y;
            red[wave][c][2] = acc.z;
            red[wave][c][3] = acc.w;
        }
        __syncthreads();
        if (tid < DK) {
            const int cc = tid >> 2, comp = tid & 3;
            float r = red[0][cc][comp] + red[1][cc][comp]
                    + red[2][cc][comp] + red[3][cc][comp];
            out[((size_t)h * NB + b) * DK + tid] = r;
        }
    }
}

extern "C" void kernel_launch(void* const* d_in, const int* in_sizes, int n_in,
                              void* d_out, int out_size, void* d_ws, size_t ws_size,
                              hipStream_t stream) {
    const float* Q     = (const float*)d_in[0];
    const float* K     = (const float*)d_in[1];
    const float* V     = (const float*)d_in[2];
    const int*   batch = (const int*)d_in[3];

    float* out  = (float*)d_out;                    // [NH,NB,DK]
    float* attn = out + (size_t)NH * NB * DK;       // [NH,NB,NE]

    int*   bounds = (int*)d_ws;                     // [NB+1], padded to 512 B
    float* ksc    = (float*)d_ws + 128;             // [NH,NE]
    float* mstash = ksc + (size_t)NH * NE;          // [NH*NB][2][2]

    seg_bounds_kernel<<<NE / 256, 256, 0, stream>>>(batch, bounds);

    scores_kernel<<<2048, 256, 0, stream>>>(Q, K, bounds, ksc, mstash);

    bc_kernel<<<2048, 256, 0, stream>>>(batch, ksc, mstash, V, bounds, attn, out);
}

// Round 4
// 333.615 us; speedup vs baseline: 1.0320x; 1.0295x over previous
//
#include <hip/hip_runtime.h>
#include <math.h>

#define NH 16
#define NB 64
#define DK 64
#define NE 32768

typedef float vf4 __attribute__((ext_vector_type(4)));

// ws layout (floats): [0..127] int bounds[NB+1] (padded to 512B)
//                     [128 .. 128+NH*NE)          float ksc[NH*NE]
//                     [128+NH*NE .. +4096)        float mstash[NH*NB][2][2]  (M,L per half-segment)

// Kernel 0: segment bounds from sorted batch. bounds[b] = min{e : batch[e] >= b}.
__global__ void seg_bounds_kernel(const int* __restrict__ batch, int* __restrict__ bounds) {
    int e = blockIdx.x * 256 + threadIdx.x;
    if (e >= NE) return;
    int be = batch[e];
    if (e == 0) {
        for (int b = 0; b <= be; ++b) bounds[b] = 0;
    } else {
        int bp = batch[e - 1];
        for (int b = bp + 1; b <= be; ++b) bounds[b] = e;
    }
    if (e == NE - 1) {
        for (int b = be + 1; b <= NB; ++b) bounds[b] = NE;
    }
}

// Kernel A: 2048 blocks x 256. Block g handles half-segment (task = g>>1, half = g&1).
// GROUP-COALESCED K reads: wave processes 4 edges/iter; j=lane>>4 picks the edge,
// c=lane&15 picks the float4 d-chunk -> each load instruction is 1KB contiguous.
__global__ __launch_bounds__(256) void scores_kernel(
    const float* __restrict__ Q,      // [NH, NB, DK]
    const float* __restrict__ K,      // [NH, NE, DK]
    const int*   __restrict__ bounds, // [NB+1]
    float* __restrict__ ksc_base,     // [NH, NE]
    float* __restrict__ mstash)       // [NH*NB][2][2]
{
    const int g    = blockIdx.x;       // 0..2047
    const int task = g >> 1;           // h*NB + b
    const int half = g & 1;
    const int h    = task >> 6;
    const int b    = task & (NB - 1);
    const int tid  = threadIdx.x;
    const int wave = tid >> 6;
    const int lane = tid & 63;
    const int j    = lane >> 4;        // edge offset within group of 4
    const int c    = lane & 15;        // float4 chunk of d

    const int start = bounds[b];
    const int end   = bounds[b + 1];
    const int S     = end - start;
    const int Sh    = (S + 1) >> 1;
    const int s0    = start + half * Sh;
    const int e1    = (s0 + Sh < end) ? s0 + Sh : end;

    float* ksc = ksc_base + (size_t)h * NE;

    __shared__ float qs[DK];
    __shared__ float sm[4], sl[4];
    if (tid < DK) qs[tid] = Q[((size_t)h * NB + b) * DK + tid];
    __syncthreads();

    const float4 qc = ((const float4*)qs)[c];
    const float4* K4 = (const float4*)(K + (size_t)h * NE * DK);

    float m = -INFINITY, l = 0.f;
    for (int e = s0 + wave * 4; e < e1; e += 16) {
        const int  ej    = e + j;
        const bool valid = ej < e1;
        const int  el    = valid ? ej : e1 - 1;
        const float4 kv = K4[(size_t)el * (DK / 4) + c];   // 1KB contiguous per wave instr
        float s = fmaf(kv.x, qc.x, fmaf(kv.y, qc.y, fmaf(kv.z, qc.z, kv.w * qc.w)));
        #pragma unroll
        for (int off = 1; off < 16; off <<= 1)
            s += __shfl_xor(s, off);
        if (valid) {
            if (c == 0) ksc[ej] = s;
            float nm = fmaxf(m, s);
            l = l * __expf(m - nm) + __expf(s - nm);
            m = nm;
        }
    }

    // merge the 4 j-groups
    #pragma unroll
    for (int off = 16; off < 64; off <<= 1) {
        float om = __shfl_xor(m, off);
        float ol = __shfl_xor(l, off);
        float nm = fmaxf(m, om);
        float t1 = (l  > 0.f) ? l  * __expf(m  - nm) : 0.f;
        float t2 = (ol > 0.f) ? ol * __expf(om - nm) : 0.f;
        m = nm; l = t1 + t2;
    }
    if (lane == 0) { sm[wave] = m; sl[wave] = l; }
    __syncthreads();

    if (tid == 0) {
        float M = -INFINITY;
        #pragma unroll
        for (int w = 0; w < 4; ++w) M = fmaxf(M, sm[w]);
        float L = 0.f;
        #pragma unroll
        for (int w = 0; w < 4; ++w) L += (sl[w] > 0.f) ? sl[w] * __expf(sm[w] - M) : 0.f;
        mstash[(task * 2 + half) * 2 + 0] = M;
        mstash[(task * 2 + half) * 2 + 1] = L;
    }
}

// Kernel BC: 2048 blocks x 256, roles interleaved by block parity so the attn
// write stream (B) and the V read stream (C) duplex uniformly per CU and in time.
// All attn stores are PLAIN vf4 stores — the rocclr fill kernel sustains 6.7 TB/s
// with plain stores while every nontemporal variant of this kernel sat at ~2 TB/s.
__global__ __launch_bounds__(256) void bc_kernel(
    const int*   __restrict__ batch,    // [NE]
    const float* __restrict__ ksc_base, // [NH, NE]
    const float* __restrict__ mstash,   // [NH*NB][2][2]
    const float* __restrict__ V,        // [NH, NE, DK]
    const int*   __restrict__ bounds,   // [NB+1]
    float* __restrict__ attn,           // [NH, NB, NE]
    float* __restrict__ out)            // [NH, NB, DK]
{
    const int blk = blockIdx.x;
    const int tid = threadIdx.x;
    __shared__ float red[4][16][4];

    if ((blk & 1) == 0) {
        // ---- B: full attn array as one coalesced plain write stream ----
        const int wb = blk >> 1;                 // 0..1023
        const unsigned total = (unsigned)NH * NB * (NE / 4);
        for (unsigned idx = wb * 256u + tid; idx < total; idx += 1024u * 256u) {
            const int e4 = idx & (NE / 4 - 1);
            const int bh = idx >> 13;            // NE/4 = 2^13
            const int b  = bh & (NB - 1);
            const int e0 = e4 << 2;
            const int4 bt = *(const int4*)(batch + e0);
            vf4 r = (vf4)(0.f);
            if (bt.x == b || bt.y == b || bt.z == b || bt.w == b) {
                const float m0 = mstash[bh * 4 + 0], l0 = mstash[bh * 4 + 1];
                const float m1 = mstash[bh * 4 + 2], l1 = mstash[bh * 4 + 3];
                const float M = fmaxf(m0, m1);
                float L = 0.f;
                if (l0 > 0.f) L += l0 * __expf(m0 - M);
                if (l1 > 0.f) L += l1 * __expf(m1 - M);
                const float inv = (L > 0.f) ? 1.f / L : 0.f;
                const int h = bh >> 6;
                const float4 s = *(const float4*)(ksc_base + (size_t)h * NE + e0);
                if (bt.x == b) r.x = __expf(s.x - M) * inv;
                if (bt.y == b) r.y = __expf(s.y - M) * inv;
                if (bt.z == b) r.z = __expf(s.z - M) * inv;
                if (bt.w == b) r.w = __expf(s.w - M) * inv;
            }
            *((vf4*)attn + idx) = r;             // plain store
        }
    } else {
        // ---- C: out[h,b,:] = sum_e p_e * V[e,:], group-coalesced V reads ----
        const int task = blk >> 1;               // h*NB + b
        const int h    = task >> 6;
        const int b    = task & (NB - 1);
        const int wave = tid >> 6;
        const int lane = tid & 63;
        const int j    = lane >> 4;
        const int c    = lane & 15;

        const int start = bounds[b];
        const int end   = bounds[b + 1];

        const float m0 = mstash[task * 4 + 0], l0 = mstash[task * 4 + 1];
        const float m1 = mstash[task * 4 + 2], l1 = mstash[task * 4 + 3];
        const float M = fmaxf(m0, m1);
        float L = 0.f;
        if (l0 > 0.f) L += l0 * __expf(m0 - M);
        if (l1 > 0.f) L += l1 * __expf(m1 - M);
        const float inv = (L > 0.f) ? 1.f / L : 0.f;

        const float*  ksc = ksc_base + (size_t)h * NE;
        const float4* V4  = (const float4*)(V + (size_t)h * NE * DK);

        float4 acc = make_float4(0.f, 0.f, 0.f, 0.f);
        #pragma unroll 2
        for (int e = start + wave * 4; e < end; e += 16) {
            const int  ej    = e + j;
            const bool valid = ej < end;
            const int  el    = valid ? ej : end - 1;
            const float p = valid ? __expf(ksc[ej] - M) * inv : 0.f;
            const float4 v = V4[(size_t)el * (DK / 4) + c];   // 1KB contiguous per wave instr
            acc.x = fmaf(p, v.x, acc.x);
            acc.y = fmaf(p, v.y, acc.y);
            acc.z = fmaf(p, v.z, acc.z);
            acc.w = fmaf(p, v.w, acc.w);
        }
        #pragma unroll
        for (int off = 16; off < 64; off <<= 1) {
            acc.x += __shfl_xor(acc.x, off);
            acc.y += __shfl_xor(acc.y, off);
            acc.z += __shfl_xor(acc.z, off);
            acc.w += __shfl_xor(acc.w, off);
        }
        if (lane < 16) {
            red[wave][c][0] = acc.x;
            red[wave][c][1] = acc.y;
            red[wave][c][2] = acc.z;
            red[wave][c][3] = acc.w;
        }
        __syncthreads();
        if (tid < DK) {
            const int cc = tid >> 2, comp = tid & 3;
            float r = red[0][cc][comp] + red[1][cc][comp]
                    + red[2][cc][comp] + red[3][cc][comp];
            out[((size_t)h * NB + b) * DK + tid] = r;
        }
    }
}

extern "C" void kernel_launch(void* const* d_in, const int* in_sizes, int n_in,
                              void* d_out, int out_size, void* d_ws, size_t ws_size,
                              hipStream_t stream) {
    const float* Q     = (const float*)d_in[0];
    const float* K     = (const float*)d_in[1];
    const float* V     = (const float*)d_in[2];
    const int*   batch = (const int*)d_in[3];

    float* out  = (float*)d_out;                    // [NH,NB,DK]
    float* attn = out + (size_t)NH * NB * DK;       // [NH,NB,NE]

    int*   bounds = (int*)d_ws;                     // [NB+1], padded to 512 B
    float* ksc    = (float*)d_ws + 128;             // [NH,NE]
    float* mstash = ksc + (size_t)NH * NE;          // [NH*NB][2][2]

    seg_bounds_kernel<<<NE / 256, 256, 0, stream>>>(batch, bounds);

    scores_kernel<<<2048, 256, 0, stream>>>(Q, K, bounds, ksc, mstash);

    bc_kernel<<<2048, 256, 0, stream>>>(batch, ksc, mstash, V, bounds, attn, out);
}

// Round 5
// 330.841 us; speedup vs baseline: 1.0407x; 1.0084x over previous
//
#include <hip/hip_runtime.h>
#include <math.h>

#define NH 16
#define NB 64
#define DK 64
#define NE 32768

typedef float vf4 __attribute__((ext_vector_type(4)));

// ws layout (floats): [0..127] int bounds[NB+1] (padded to 512B)
//                     [128 .. 128+NH*NE)          float ksc[NH*NE]
//                     [128+NH*NE .. +4096)        float mstash[NH*NB][2][2]  (M,L per half-segment)

// Kernel 0: segment bounds from sorted batch. bounds[b] = min{e : batch[e] >= b}.
__global__ void seg_bounds_kernel(const int* __restrict__ batch, int* __restrict__ bounds) {
    int e = blockIdx.x * 256 + threadIdx.x;
    if (e >= NE) return;
    int be = batch[e];
    if (e == 0) {
        for (int b = 0; b <= be; ++b) bounds[b] = 0;
    } else {
        int bp = batch[e - 1];
        for (int b = bp + 1; b <= be; ++b) bounds[b] = e;
    }
    if (e == NE - 1) {
        for (int b = be + 1; b <= NB; ++b) bounds[b] = NE;
    }
}

// Kernel A: 2048 blocks x 256. Block g handles half-segment (task = g>>1, half = g&1).
// Group-coalesced K reads (j=lane>>4 edge, c=lane&15 d-chunk -> 1KB/wave-instr), now
// with an 8-deep load batch per super-iteration: 8 independent 1KB loads issued before
// any consumption (MLP ~8KB/wave instead of ~1KB). Online (m,l) updated ONCE per
// 32-edge super-iter (single exp-rescale chain) instead of per 4 edges.
__global__ __launch_bounds__(256) void scores_kernel(
    const float* __restrict__ Q,      // [NH, NB, DK]
    const float* __restrict__ K,      // [NH, NE, DK]
    const int*   __restrict__ bounds, // [NB+1]
    float* __restrict__ ksc_base,     // [NH, NE]
    float* __restrict__ mstash)       // [NH*NB][2][2]
{
    const int g    = blockIdx.x;       // 0..2047
    const int task = g >> 1;           // h*NB + b
    const int half = g & 1;
    const int h    = task >> 6;
    const int b    = task & (NB - 1);
    const int tid  = threadIdx.x;
    const int wave = tid >> 6;
    const int lane = tid & 63;
    const int j    = lane >> 4;        // edge offset within group of 4
    const int c    = lane & 15;        // float4 chunk of d

    const int start = bounds[b];
    const int end   = bounds[b + 1];
    const int S     = end - start;
    const int Sh    = (S + 1) >> 1;
    const int s0    = start + half * Sh;
    const int e1    = (s0 + Sh < end) ? s0 + Sh : end;

    float* ksc = ksc_base + (size_t)h * NE;

    __shared__ float qs[DK];
    __shared__ float sm[4], sl[4];
    if (tid < DK) qs[tid] = Q[((size_t)h * NB + b) * DK + tid];
    __syncthreads();

    const float4 qc = ((const float4*)qs)[c];
    const float4* K4 = (const float4*)(K + (size_t)h * NE * DK);

    float m = -INFINITY, l = 0.f;
    int e = s0 + wave * 4;

    // ---- main: 8 sub-iters (32 edges/wave) with all 8 loads in flight ----
    for (; e + 115 < e1; e += 128) {           // max edge touched: e + 16*7 + 3
        float4 kv[8];
        #pragma unroll
        for (int u = 0; u < 8; ++u)
            kv[u] = K4[(size_t)(e + 16 * u + j) * (DK / 4) + c];
        float s[8];
        #pragma unroll
        for (int u = 0; u < 8; ++u) {
            float t = fmaf(kv[u].x, qc.x, fmaf(kv[u].y, qc.y,
                      fmaf(kv[u].z, qc.z, kv[u].w * qc.w)));
            #pragma unroll
            for (int off = 1; off < 16; off <<= 1)
                t += __shfl_xor(t, off);       // full dot, broadcast in 16-lane group
            s[u] = t;
            if (c == 0) ksc[e + 16 * u + j] = t;
        }
        float mx = fmaxf(fmaxf(fmaxf(s[0], s[1]), fmaxf(s[2], s[3])),
                         fmaxf(fmaxf(s[4], s[5]), fmaxf(s[6], s[7])));
        const float nm = fmaxf(m, mx);
        float sum = 0.f;
        #pragma unroll
        for (int u = 0; u < 8; ++u) sum += __expf(s[u] - nm);   // 8 independent exps
        l = l * __expf(m - nm) + sum;          // m=-inf first time: exp(-inf)=0, l=0 -> 0
        m = nm;
    }
    // ---- tail: clamped single-group iterations ----
    for (; e < e1; e += 16) {
        const int  ej    = e + j;
        const bool valid = ej < e1;
        const int  el    = valid ? ej : e1 - 1;
        const float4 kv = K4[(size_t)el * (DK / 4) + c];
        float s = fmaf(kv.x, qc.x, fmaf(kv.y, qc.y, fmaf(kv.z, qc.z, kv.w * qc.w)));
        #pragma unroll
        for (int off = 1; off < 16; off <<= 1)
            s += __shfl_xor(s, off);
        if (valid) {
            if (c == 0) ksc[ej] = s;
            float nm = fmaxf(m, s);
            l = l * __expf(m - nm) + __expf(s - nm);
            m = nm;
        }
    }

    // merge the 4 j-groups (lanes with equal c hold identical (m,l))
    #pragma unroll
    for (int off = 16; off < 64; off <<= 1) {
        float om = __shfl_xor(m, off);
        float ol = __shfl_xor(l, off);
        float nm = fmaxf(m, om);
        float t1 = (l  > 0.f) ? l  * __expf(m  - nm) : 0.f;
        float t2 = (ol > 0.f) ? ol * __expf(om - nm) : 0.f;
        m = nm; l = t1 + t2;
    }
    if (lane == 0) { sm[wave] = m; sl[wave] = l; }
    __syncthreads();

    if (tid == 0) {
        float M = -INFINITY;
        #pragma unroll
        for (int w = 0; w < 4; ++w) M = fmaxf(M, sm[w]);
        float L = 0.f;
        #pragma unroll
        for (int w = 0; w < 4; ++w) L += (sl[w] > 0.f) ? sl[w] * __expf(sm[w] - M) : 0.f;
        mstash[(task * 2 + half) * 2 + 0] = M;
        mstash[(task * 2 + half) * 2 + 1] = L;
    }
}

// Kernel BC: 2048 blocks x 256, roles interleaved by block parity (write stream B and
// V-read stream C duplex per CU). B: plain vf4 stores (stores never stall). C: 8-deep
// load batch per super-iteration (8x 1KB V loads + 8 scalar ksc loads in flight).
__global__ __launch_bounds__(256) void bc_kernel(
    const int*   __restrict__ batch,    // [NE]
    const float* __restrict__ ksc_base, // [NH, NE]
    const float* __restrict__ mstash,   // [NH*NB][2][2]
    const float* __restrict__ V,        // [NH, NE, DK]
    const int*   __restrict__ bounds,   // [NB+1]
    float* __restrict__ attn,           // [NH, NB, NE]
    float* __restrict__ out)            // [NH, NB, DK]
{
    const int blk = blockIdx.x;
    const int tid = threadIdx.x;
    __shared__ float red[4][16][4];

    if ((blk & 1) == 0) {
        // ---- B: full attn array as one coalesced plain write stream ----
        const int wb = blk >> 1;                 // 0..1023
        const unsigned total = (unsigned)NH * NB * (NE / 4);
        for (unsigned idx = wb * 256u + tid; idx < total; idx += 1024u * 256u) {
            const int e4 = idx & (NE / 4 - 1);
            const int bh = idx >> 13;            // NE/4 = 2^13
            const int b  = bh & (NB - 1);
            const int e0 = e4 << 2;
            const int4 bt = *(const int4*)(batch + e0);
            vf4 r = (vf4)(0.f);
            if (bt.x == b || bt.y == b || bt.z == b || bt.w == b) {
                const float m0 = mstash[bh * 4 + 0], l0 = mstash[bh * 4 + 1];
                const float m1 = mstash[bh * 4 + 2], l1 = mstash[bh * 4 + 3];
                const float M = fmaxf(m0, m1);
                float L = 0.f;
                if (l0 > 0.f) L += l0 * __expf(m0 - M);
                if (l1 > 0.f) L += l1 * __expf(m1 - M);
                const float inv = (L > 0.f) ? 1.f / L : 0.f;
                const int h = bh >> 6;
                const float4 s = *(const float4*)(ksc_base + (size_t)h * NE + e0);
                if (bt.x == b) r.x = __expf(s.x - M) * inv;
                if (bt.y == b) r.y = __expf(s.y - M) * inv;
                if (bt.z == b) r.z = __expf(s.z - M) * inv;
                if (bt.w == b) r.w = __expf(s.w - M) * inv;
            }
            *((vf4*)attn + idx) = r;             // plain store
        }
    } else {
        // ---- C: out[h,b,:] = sum_e p_e * V[e,:], 8-deep batched V reads ----
        const int task = blk >> 1;               // h*NB + b
        const int h    = task >> 6;
        const int b    = task & (NB - 1);
        const int wave = tid >> 6;
        const int lane = tid & 63;
        const int j    = lane >> 4;
        const int c    = lane & 15;

        const int start = bounds[b];
        const int end   = bounds[b + 1];

        const float m0 = mstash[task * 4 + 0], l0 = mstash[task * 4 + 1];
        const float m1 = mstash[task * 4 + 2], l1 = mstash[task * 4 + 3];
        const float M = fmaxf(m0, m1);
        float L = 0.f;
        if (l0 > 0.f) L += l0 * __expf(m0 - M);
        if (l1 > 0.f) L += l1 * __expf(m1 - M);
        const float inv = (L > 0.f) ? 1.f / L : 0.f;

        const float*  ksc = ksc_base + (size_t)h * NE;
        const float4* V4  = (const float4*)(V + (size_t)h * NE * DK);

        float4 acc = make_float4(0.f, 0.f, 0.f, 0.f);
        int e = start + wave * 4;

        // main: 8 sub-iters, all 16 loads issued before any consumption
        for (; e + 115 < end; e += 128) {
            float4 v[8]; float p[8];
            #pragma unroll
            for (int u = 0; u < 8; ++u) {
                const int ej = e + 16 * u + j;
                p[u] = ksc[ej];                              // 1 line per 16-lane group
                v[u] = V4[(size_t)ej * (DK / 4) + c];        // 1KB contiguous per wave instr
            }
            #pragma unroll
            for (int u = 0; u < 8; ++u) {
                const float pe = __expf(p[u] - M) * inv;
                acc.x = fmaf(pe, v[u].x, acc.x);
                acc.y = fmaf(pe, v[u].y, acc.y);
                acc.z = fmaf(pe, v[u].z, acc.z);
                acc.w = fmaf(pe, v[u].w, acc.w);
            }
        }
        // tail: clamped
        for (; e < end; e += 16) {
            const int  ej    = e + j;
            const bool valid = ej < end;
            const int  el    = valid ? ej : end - 1;
            const float pe = valid ? __expf(ksc[ej] - M) * inv : 0.f;
            const float4 v = V4[(size_t)el * (DK / 4) + c];
            acc.x = fmaf(pe, v.x, acc.x);
            acc.y = fmaf(pe, v.y, acc.y);
            acc.z = fmaf(pe, v.z, acc.z);
            acc.w = fmaf(pe, v.w, acc.w);
        }

        #pragma unroll
        for (int off = 16; off < 64; off <<= 1) {
            acc.x += __shfl_xor(acc.x, off);
            acc.y += __shfl_xor(acc.y, off);
            acc.z += __shfl_xor(acc.z, off);
            acc.w += __shfl_xor(acc.w, off);
        }
        if (lane < 16) {
            red[wave][c][0] = acc.x;
            red[wave][c][1] = acc.y;
            red[wave][c][2] = acc.z;
            red[wave][c][3] = acc.w;
        }
        __syncthreads();
        if (tid < DK) {
            const int cc = tid >> 2, comp = tid & 3;
            float r = red[0][cc][comp] + red[1][cc][comp]
                    + red[2][cc][comp] + red[3][cc][comp];
            out[((size_t)h * NB + b) * DK + tid] = r;
        }
    }
}

extern "C" void kernel_launch(void* const* d_in, const int* in_sizes, int n_in,
                              void* d_out, int out_size, void* d_ws, size_t ws_size,
                              hipStream_t stream) {
    const float* Q     = (const float*)d_in[0];
    const float* K     = (const float*)d_in[1];
    const float* V     = (const float*)d_in[2];
    const int*   batch = (const int*)d_in[3];

    float* out  = (float*)d_out;                    // [NH,NB,DK]
    float* attn = out + (size_t)NH * NB * DK;       // [NH,NB,NE]

    int*   bounds = (int*)d_ws;                     // [NB+1], padded to 512 B
    float* ksc    = (float*)d_ws + 128;             // [NH,NE]
    float* mstash = ksc + (size_t)NH * NE;          // [NH*NB][2][2]

    seg_bounds_kernel<<<NE / 256, 256, 0, stream>>>(batch, bounds);

    scores_kernel<<<2048, 256, 0, stream>>>(Q, K, bounds, ksc, mstash);

    bc_kernel<<<2048, 256, 0, stream>>>(batch, ksc, mstash, V, bounds, attn, out);
}

// Round 7
// 324.248 us; speedup vs baseline: 1.0618x; 1.0203x over previous
//
#include <hip/hip_runtime.h>
#include <math.h>

#define NH 16
#define NB 64
#define DK 64
#define NE 32768
#define LDS_CAP 2048   // max edges whose scores live in LDS at once (bench segments ~512)

typedef float vf4 __attribute__((ext_vector_type(4)));

// ws layout: [0..127] int bounds[NB+1] (padded to 512B). ksc/mstash no longer needed.

// Kernel 0: segment bounds from sorted batch. bounds[b] = min{e : batch[e] >= b}.
__global__ void seg_bounds_kernel(const int* __restrict__ batch, int* __restrict__ bounds) {
    int e = blockIdx.x * 256 + threadIdx.x;
    if (e >= NE) return;
    int be = batch[e];
    if (e == 0) {
        for (int b = 0; b <= be; ++b) bounds[b] = 0;
    } else {
        int bp = batch[e - 1];
        for (int b = bp + 1; b <= be; ++b) bounds[b] = e;
    }
    if (e == NE - 1) {
        for (int b = be + 1; b <= NB; ++b) bounds[b] = NE;
    }
}

// Fused kernel: one block per (h,b). 256 threads = 4 waves.
// Pass 1: group-coalesced K reads (j=lane>>4 edge, c=lane&15 d-chunk -> 1KB/wave-instr),
//         8-deep load batches; scores -> LDS; per-lane online (m,l), merged once/32 edges.
// Reduce: (m,l) -> block M, inv.
// Zero:   attn complement [0,start) U [end,NE) with plain vf4 stores (fire-and-forget;
//         overlaps the V-read stream below).
// P:      normalized p into [start,end) straight from LDS (no HBM round-trip).
// Pass 2: out[d] = sum_e p_e * V[e][d], 8-deep batched 1KB V loads, p from LDS.
// Fallback (S > LDS_CAP, never hit by bench input): chunked recompute, still exact.
__global__ __launch_bounds__(256) void fused_kernel(
    const float* __restrict__ Q,      // [NH, NB, DK]
    const float* __restrict__ K,      // [NH, NE, DK]
    const float* __restrict__ V,      // [NH, NE, DK]
    const int*   __restrict__ bounds, // [NB+1]
    float* __restrict__ out,          // [NH, NB, DK]
    float* __restrict__ attn)         // [NH, NB, NE]
{
    const int task = blockIdx.x;      // h*NB + b
    const int h    = task >> 6;
    const int b    = task & (NB - 1);
    const int tid  = threadIdx.x;
    const int wave = tid >> 6;
    const int lane = tid & 63;
    const int j    = lane >> 4;       // edge offset within group of 4
    const int c    = lane & 15;       // float4 chunk of d

    const int start = bounds[b];
    const int end   = bounds[b + 1];
    const int S     = end - start;
    const bool single = (S <= LDS_CAP);

    __shared__ float qs[DK];
    __shared__ float ssc[LDS_CAP];
    __shared__ float sm[4], sl[4];
    __shared__ float bM, bInv;
    __shared__ float red[4][16][4];

    if (tid < DK) qs[tid] = Q[((size_t)h * NB + b) * DK + tid];
    __syncthreads();

    const float4  qc  = ((const float4*)qs)[c];
    const float4* K4  = (const float4*)(K + (size_t)h * NE * DK);
    const float4* V4  = (const float4*)(V + (size_t)h * NE * DK);
    float* arow = attn + ((size_t)h * NB + b) * NE;

    // ---- Pass 1: scores + online (m,l) over the whole segment ----
    float m = -INFINITY, l = 0.f;
    int e = start + wave * 4;
    for (; e + 115 < end; e += 128) {          // 8 sub-iters, 8 loads in flight
        float4 kv[8];
        #pragma unroll
        for (int u = 0; u < 8; ++u)
            kv[u] = K4[(size_t)(e + 16 * u + j) * (DK / 4) + c];
        float s[8];
        #pragma unroll
        for (int u = 0; u < 8; ++u) {
            float t = fmaf(kv[u].x, qc.x, fmaf(kv[u].y, qc.y,
                      fmaf(kv[u].z, qc.z, kv[u].w * qc.w)));
            #pragma unroll
            for (int off = 1; off < 16; off <<= 1)
                t += __shfl_xor(t, off);       // full dot, broadcast in 16-lane group
            s[u] = t;
            if (single && c == 0) ssc[e + 16 * u + j - start] = t;
        }
        float mx = fmaxf(fmaxf(fmaxf(s[0], s[1]), fmaxf(s[2], s[3])),
                         fmaxf(fmaxf(s[4], s[5]), fmaxf(s[6], s[7])));
        const float nm = fmaxf(m, mx);
        float sum = 0.f;
        #pragma unroll
        for (int u = 0; u < 8; ++u) sum += __expf(s[u] - nm);
        l = l * __expf(m - nm) + sum;          // m=-inf first time: 0 contribution, safe
        m = nm;
    }
    for (; e < end; e += 16) {                 // clamped tail
        const int  ej    = e + j;
        const bool valid = ej < end;
        const int  el    = valid ? ej : end - 1;
        const float4 kv = K4[(size_t)el * (DK / 4) + c];
        float t = fmaf(kv.x, qc.x, fmaf(kv.y, qc.y, fmaf(kv.z, qc.z, kv.w * qc.w)));
        #pragma unroll
        for (int off = 1; off < 16; off <<= 1)
            t += __shfl_xor(t, off);
        if (valid) {
            if (single && c == 0) ssc[ej - start] = t;
            float nm = fmaxf(m, t);
            l = l * __expf(m - nm) + __expf(t - nm);
            m = nm;
        }
    }

    // ---- (m,l): merge j-groups, then waves ----
    #pragma unroll
    for (int off = 16; off < 64; off <<= 1) {
        float om = __shfl_xor(m, off);
        float ol = __shfl_xor(l, off);
        float nm = fmaxf(m, om);
        float t1 = (l  > 0.f) ? l  * __expf(m  - nm) : 0.f;
        float t2 = (ol > 0.f) ? ol * __expf(om - nm) : 0.f;
        m = nm; l = t1 + t2;
    }
    if (lane == 0) { sm[wave] = m; sl[wave] = l; }
    __syncthreads();                           // also publishes ssc writes
    if (tid == 0) {
        float M = -INFINITY;
        #pragma unroll
        for (int w = 0; w < 4; ++w) M = fmaxf(M, sm[w]);
        float L = 0.f;
        #pragma unroll
        for (int w = 0; w < 4; ++w) L += (sl[w] > 0.f) ? sl[w] * __expf(sm[w] - M) : 0.f;
        bM = M; bInv = (L > 0.f) ? 1.f / L : 0.f;
    }
    __syncthreads();
    const float M   = bM;
    const float inv = bInv;

    // ---- Zero-fill attn complement (plain vf4 stores; overlaps V reads below) ----
    {
        vf4 z4 = (vf4)(0.f);
        vf4* arow4 = (vf4*)arow;
        const int zs = start >> 2;
        const int ze = (end + 3) >> 2;
        for (int i = tid; i < zs; i += 256) arow4[i] = z4;
        for (int i = ze + tid; i < NE / 4; i += 256) arow4[i] = z4;
        if (tid == 0) {
            for (int p = (zs << 2); p < start; ++p) arow[p] = 0.f;
        } else if (tid == 1) {
            for (int p = end; p < (ze << 2); ++p) arow[p] = 0.f;
        }
    }

    float4 acc = make_float4(0.f, 0.f, 0.f, 0.f);

    if (single) {
        // ---- p-writes straight from LDS ----
        for (int ep = start + tid; ep < end; ep += 256)
            arow[ep] = __expf(ssc[ep - start] - M) * inv;

        // ---- Pass 2: V accumulation, 8-deep batches, p from LDS ----
        int ev = start + wave * 4;
        for (; ev + 115 < end; ev += 128) {
            float4 v[8]; float p[8];
            #pragma unroll
            for (int u = 0; u < 8; ++u) {
                const int ej = ev + 16 * u + j;
                p[u] = ssc[ej - start];                       // LDS broadcast across c
                v[u] = V4[(size_t)ej * (DK / 4) + c];         // 1KB contiguous per wave instr
            }
            #pragma unroll
            for (int u = 0; u < 8; ++u) {
                const float pe = __expf(p[u] - M) * inv;
                acc.x = fmaf(pe, v[u].x, acc.x);
                acc.y = fmaf(pe, v[u].y, acc.y);
                acc.z = fmaf(pe, v[u].z, acc.z);
                acc.w = fmaf(pe, v[u].w, acc.w);
            }
        }
        for (; ev < end; ev += 16) {
            const int  ej    = ev + j;
            const bool valid = ej < end;
            const int  el    = valid ? ej : end - 1;
            const float pe = valid ? __expf(ssc[el - start] - M) * inv : 0.f;
            const float4 v = V4[(size_t)el * (DK / 4) + c];
            acc.x = fmaf(pe, v.x, acc.x);
            acc.y = fmaf(pe, v.y, acc.y);
            acc.z = fmaf(pe, v.z, acc.z);
            acc.w = fmaf(pe, v.w, acc.w);
        }
    } else {
        // ---- Fallback: chunked recompute (exact; not hit by bench input) ----
        for (int cs = start; cs < end; cs += LDS_CAP) {
            const int ce = (cs + LDS_CAP < end) ? cs + LDS_CAP : end;
            __syncthreads();                   // previous chunk consumers done
            for (int ek = cs + wave * 4; ek < ce; ek += 16) {
                const int  ej    = ek + j;
                const bool valid = ej < ce;
                const int  el    = valid ? ej : ce - 1;
                const float4 kv = K4[(size_t)el * (DK / 4) + c];
                float t = fmaf(kv.x, qc.x, fmaf(kv.y, qc.y, fmaf(kv.z, qc.z, kv.w * qc.w)));
                #pragma unroll
                for (int off = 1; off < 16; off <<= 1)
                    t += __shfl_xor(t, off);
                if (valid && c == 0) ssc[el - cs] = t;
            }
            __syncthreads();
            for (int ep = cs + tid; ep < ce; ep += 256)
                arow[ep] = __expf(ssc[ep - cs] - M) * inv;
            for (int ev = cs + wave * 4; ev < ce; ev += 16) {
                const int  ej    = ev + j;
                const bool valid = ej < ce;
                const int  el    = valid ? ej : ce - 1;
                const float pe = valid ? __expf(ssc[el - cs] - M) * inv : 0.f;
                const float4 v = V4[(size_t)el * (DK / 4) + c];
                acc.x = fmaf(pe, v.x, acc.x);
                acc.y = fmaf(pe, v.y, acc.y);
                acc.z = fmaf(pe, v.z, acc.z);
                acc.w = fmaf(pe, v.w, acc.w);
            }
        }
    }

    // ---- cross-wave out reduce ----
    #pragma unroll
    for (int off = 16; off < 64; off <<= 1) {
        acc.x += __shfl_xor(acc.x, off);
        acc.y += __shfl_xor(acc.y, off);
        acc.z += __shfl_xor(acc.z, off);
        acc.w += __shfl_xor(acc.w, off);
    }
    if (lane < 16) {
        red[wave][c][0] = acc.x;
        red[wave][c][1] = acc.y;
        red[wave][c][2] = acc.z;
        red[wave][c][3] = acc.w;
    }
    __syncthreads();
    if (tid < DK) {
        const int cc = tid >> 2, comp = tid & 3;
        float r = red[0][cc][comp] + red[1][cc][comp]
                + red[2][cc][comp] + red[3][cc][comp];
        out[((size_t)h * NB + b) * DK + tid] = r;
    }
}

extern "C" void kernel_launch(void* const* d_in, const int* in_sizes, int n_in,
                              void* d_out, int out_size, void* d_ws, size_t ws_size,
                              hipStream_t stream) {
    const float* Q     = (const float*)d_in[0];
    const float* K     = (const float*)d_in[1];
    const float* V     = (const float*)d_in[2];
    const int*   batch = (const int*)d_in[3];

    float* out  = (float*)d_out;                    // [NH,NB,DK]
    float* attn = out + (size_t)NH * NB * DK;       // [NH,NB,NE]

    int*   bounds = (int*)d_ws;                     // [NB+1]

    seg_bounds_kernel<<<NE / 256, 256, 0, stream>>>(batch, bounds);

    fused_kernel<<<NH * NB, 256, 0, stream>>>(Q, K, V, bounds, out, attn);
}

// Round 8
// 322.672 us; speedup vs baseline: 1.0670x; 1.0049x over previous
//
#include <hip/hip_runtime.h>
#include <math.h>

#define NH 16
#define NB 64
#define DK 64
#define NE 32768
#define LDS_CAP 2048   // max edges whose scores live in LDS at once (bench segments ~512)

typedef float vf4 __attribute__((ext_vector_type(4)));

// ws layout: [0..127] int bounds[NB+1] (padded to 512B).

// Kernel 0: segment bounds from sorted batch. bounds[b] = min{e : batch[e] >= b}.
__global__ void seg_bounds_kernel(const int* __restrict__ batch, int* __restrict__ bounds) {
    int e = blockIdx.x * 256 + threadIdx.x;
    if (e >= NE) return;
    int be = batch[e];
    if (e == 0) {
        for (int b = 0; b <= be; ++b) bounds[b] = 0;
    } else {
        int bp = batch[e - 1];
        for (int b = bp + 1; b <= be; ++b) bounds[b] = e;
    }
    if (e == NE - 1) {
        for (int b = be + 1; b <= NB; ++b) bounds[b] = NE;
    }
}

// Fused kernel: one block per (h,b). 256 threads = 4 waves.
// R7 + sched_barrier(0) after each 8-load batch. R7's VGPR_Count=32 proved the
// compiler re-serialized the "8 loads in flight" batch (kv[8] alone needs 32 VGPRs);
// the barrier forces all 8 loads issued before any consumer -> true 8KB/wave MLP.
__global__ __launch_bounds__(256) void fused_kernel(
    const float* __restrict__ Q,      // [NH, NB, DK]
    const float* __restrict__ K,      // [NH, NE, DK]
    const float* __restrict__ V,      // [NH, NE, DK]
    const int*   __restrict__ bounds, // [NB+1]
    float* __restrict__ out,          // [NH, NB, DK]
    float* __restrict__ attn)         // [NH, NB, NE]
{
    const int task = blockIdx.x;      // h*NB + b
    const int h    = task >> 6;
    const int b    = task & (NB - 1);
    const int tid  = threadIdx.x;
    const int wave = tid >> 6;
    const int lane = tid & 63;
    const int j    = lane >> 4;       // edge offset within group of 4
    const int c    = lane & 15;       // float4 chunk of d

    const int start = bounds[b];
    const int end   = bounds[b + 1];
    const int S     = end - start;
    const bool single = (S <= LDS_CAP);

    __shared__ float qs[DK];
    __shared__ float ssc[LDS_CAP];
    __shared__ float sm[4], sl[4];
    __shared__ float bM, bInv;
    __shared__ float red[4][16][4];

    if (tid < DK) qs[tid] = Q[((size_t)h * NB + b) * DK + tid];
    __syncthreads();

    const float4  qc  = ((const float4*)qs)[c];
    const float4* K4  = (const float4*)(K + (size_t)h * NE * DK);
    const float4* V4  = (const float4*)(V + (size_t)h * NE * DK);
    float* arow = attn + ((size_t)h * NB + b) * NE;

    // ---- Pass 1: scores + online (m,l) over the whole segment ----
    float m = -INFINITY, l = 0.f;
    int e = start + wave * 4;
    for (; e + 115 < end; e += 128) {          // 8 sub-iters, 8 loads in flight
        float4 kv[8];
        #pragma unroll
        for (int u = 0; u < 8; ++u)
            kv[u] = K4[(size_t)(e + 16 * u + j) * (DK / 4) + c];
        __builtin_amdgcn_sched_barrier(0);     // pin: all 8 loads issued before any consumer
        float s[8];
        #pragma unroll
        for (int u = 0; u < 8; ++u) {
            float t = fmaf(kv[u].x, qc.x, fmaf(kv[u].y, qc.y,
                      fmaf(kv[u].z, qc.z, kv[u].w * qc.w)));
            #pragma unroll
            for (int off = 1; off < 16; off <<= 1)
                t += __shfl_xor(t, off);       // full dot, broadcast in 16-lane group
            s[u] = t;
            if (single && c == 0) ssc[e + 16 * u + j - start] = t;
        }
        float mx = fmaxf(fmaxf(fmaxf(s[0], s[1]), fmaxf(s[2], s[3])),
                         fmaxf(fmaxf(s[4], s[5]), fmaxf(s[6], s[7])));
        const float nm = fmaxf(m, mx);
        float sum = 0.f;
        #pragma unroll
        for (int u = 0; u < 8; ++u) sum += __expf(s[u] - nm);
        l = l * __expf(m - nm) + sum;          // m=-inf first time: 0 contribution, safe
        m = nm;
    }
    for (; e < end; e += 16) {                 // clamped tail
        const int  ej    = e + j;
        const bool valid = ej < end;
        const int  el    = valid ? ej : end - 1;
        const float4 kv = K4[(size_t)el * (DK / 4) + c];
        float t = fmaf(kv.x, qc.x, fmaf(kv.y, qc.y, fmaf(kv.z, qc.z, kv.w * qc.w)));
        #pragma unroll
        for (int off = 1; off < 16; off <<= 1)
            t += __shfl_xor(t, off);
        if (valid) {
            if (single && c == 0) ssc[ej - start] = t;
            float nm = fmaxf(m, t);
            l = l * __expf(m - nm) + __expf(t - nm);
            m = nm;
        }
    }

    // ---- (m,l): merge j-groups, then waves ----
    #pragma unroll
    for (int off = 16; off < 64; off <<= 1) {
        float om = __shfl_xor(m, off);
        float ol = __shfl_xor(l, off);
        float nm = fmaxf(m, om);
        float t1 = (l  > 0.f) ? l  * __expf(m  - nm) : 0.f;
        float t2 = (ol > 0.f) ? ol * __expf(om - nm) : 0.f;
        m = nm; l = t1 + t2;
    }
    if (lane == 0) { sm[wave] = m; sl[wave] = l; }
    __syncthreads();                           // also publishes ssc writes
    if (tid == 0) {
        float M = -INFINITY;
        #pragma unroll
        for (int w = 0; w < 4; ++w) M = fmaxf(M, sm[w]);
        float L = 0.f;
        #pragma unroll
        for (int w = 0; w < 4; ++w) L += (sl[w] > 0.f) ? sl[w] * __expf(sm[w] - M) : 0.f;
        bM = M; bInv = (L > 0.f) ? 1.f / L : 0.f;
    }
    __syncthreads();
    const float M   = bM;
    const float inv = bInv;

    // ---- Zero-fill attn complement (plain vf4 stores; overlaps V reads below) ----
    {
        vf4 z4 = (vf4)(0.f);
        vf4* arow4 = (vf4*)arow;
        const int zs = start >> 2;
        const int ze = (end + 3) >> 2;
        for (int i = tid; i < zs; i += 256) arow4[i] = z4;
        for (int i = ze + tid; i < NE / 4; i += 256) arow4[i] = z4;
        if (tid == 0) {
            for (int p = (zs << 2); p < start; ++p) arow[p] = 0.f;
        } else if (tid == 1) {
            for (int p = end; p < (ze << 2); ++p) arow[p] = 0.f;
        }
    }

    float4 acc = make_float4(0.f, 0.f, 0.f, 0.f);

    if (single) {
        // ---- p-writes straight from LDS ----
        for (int ep = start + tid; ep < end; ep += 256)
            arow[ep] = __expf(ssc[ep - start] - M) * inv;

        // ---- Pass 2: V accumulation, 8-deep batches, p from LDS ----
        int ev = start + wave * 4;
        for (; ev + 115 < end; ev += 128) {
            float4 v[8]; float p[8];
            #pragma unroll
            for (int u = 0; u < 8; ++u) {
                const int ej = ev + 16 * u + j;
                p[u] = ssc[ej - start];                       // LDS broadcast across c
                v[u] = V4[(size_t)ej * (DK / 4) + c];         // 1KB contiguous per wave instr
            }
            __builtin_amdgcn_sched_barrier(0);  // pin: all 8 V loads + 8 LDS reads in flight
            #pragma unroll
            for (int u = 0; u < 8; ++u) {
                const float pe = __expf(p[u] - M) * inv;
                acc.x = fmaf(pe, v[u].x, acc.x);
                acc.y = fmaf(pe, v[u].y, acc.y);
                acc.z = fmaf(pe, v[u].z, acc.z);
                acc.w = fmaf(pe, v[u].w, acc.w);
            }
        }
        for (; ev < end; ev += 16) {
            const int  ej    = ev + j;
            const bool valid = ej < end;
            const int  el    = valid ? ej : end - 1;
            const float pe = valid ? __expf(ssc[el - start] - M) * inv : 0.f;
            const float4 v = V4[(size_t)el * (DK / 4) + c];
            acc.x = fmaf(pe, v.x, acc.x);
            acc.y = fmaf(pe, v.y, acc.y);
            acc.z = fmaf(pe, v.z, acc.z);
            acc.w = fmaf(pe, v.w, acc.w);
        }
    } else {
        // ---- Fallback: chunked recompute (exact; not hit by bench input) ----
        for (int cs = start; cs < end; cs += LDS_CAP) {
            const int ce = (cs + LDS_CAP < end) ? cs + LDS_CAP : end;
            __syncthreads();                   // previous chunk consumers done
            for (int ek = cs + wave * 4; ek < ce; ek += 16) {
                const int  ej    = ek + j;
                const bool valid = ej < ce;
                const int  el    = valid ? ej : ce - 1;
                const float4 kv = K4[(size_t)el * (DK / 4) + c];
                float t = fmaf(kv.x, qc.x, fmaf(kv.y, qc.y, fmaf(kv.z, qc.z, kv.w * qc.w)));
                #pragma unroll
                for (int off = 1; off < 16; off <<= 1)
                    t += __shfl_xor(t, off);
                if (valid && c == 0) ssc[el - cs] = t;
            }
            __syncthreads();
            for (int ep = cs + tid; ep < ce; ep += 256)
                arow[ep] = __expf(ssc[ep - cs] - M) * inv;
            for (int ev = cs + wave * 4; ev < ce; ev += 16) {
                const int  ej    = ev + j;
                const bool valid = ej < ce;
                const int  el    = valid ? ej : ce - 1;
                const float pe = valid ? __expf(ssc[el - cs] - M) * inv : 0.f;
                const float4 v = V4[(size_t)el * (DK / 4) + c];
                acc.x = fmaf(pe, v.x, acc.x);
                acc.y = fmaf(pe, v.y, acc.y);
                acc.z = fmaf(pe, v.z, acc.z);
                acc.w = fmaf(pe, v.w, acc.w);
            }
        }
    }

    // ---- cross-wave out reduce ----
    #pragma unroll
    for (int off = 16; off < 64; off <<= 1) {
        acc.x += __shfl_xor(acc.x, off);
        acc.y += __shfl_xor(acc.y, off);
        acc.z += __shfl_xor(acc.z, off);
        acc.w += __shfl_xor(acc.w, off);
    }
    if (lane < 16) {
        red[wave][c][0] = acc.x;
        red[wave][c][1] = acc.y;
        red[wave][c][2] = acc.z;
        red[wave][c][3] = acc.w;
    }
    __syncthreads();
    if (tid < DK) {
        const int cc = tid >> 2, comp = tid & 3;
        float r = red[0][cc][comp] + red[1][cc][comp]
                + red[2][cc][comp] + red[3][cc][comp];
        out[((size_t)h * NB + b) * DK + tid] = r;
    }
}

extern "C" void kernel_launch(void* const* d_in, const int* in_sizes, int n_in,
                              void* d_out, int out_size, void* d_ws, size_t ws_size,
                              hipStream_t stream) {
    const float* Q     = (const float*)d_in[0];
    const float* K     = (const float*)d_in[1];
    const float* V     = (const float*)d_in[2];
    const int*   batch = (const int*)d_in[3];

    float* out  = (float*)d_out;                    // [NH,NB,DK]
    float* attn = out + (size_t)NH * NB * DK;       // [NH,NB,NE]

    int*   bounds = (int*)d_ws;                     // [NB+1]

    seg_bounds_kernel<<<NE / 256, 256, 0, stream>>>(batch, bounds);

    fused_kernel<<<NH * NB, 256, 0, stream>>>(Q, K, V, bounds, out, attn);
}